// Round 7
// baseline (252.969 us; speedup 1.0000x reference)
//
#include <hip/hip_runtime.h>
#include <hip/hip_bf16.h>
#include <stdint.h>

// ---- problem constants ----
#define BATCH 4
#define SEQ   8400
#define DM    512
#define KP    8484      // SEQ + 2*42 (edge pad)
#define NWIN  100
#define STEP_ 84
#define PAD_  42
#define NKEY  126
#define MROWS 33600     // BATCH*SEQ

typedef __attribute__((ext_vector_type(8))) short short8;
typedef __attribute__((ext_vector_type(4))) float float4v;
typedef __attribute__((ext_vector_type(4))) unsigned short ushort4v;

#define MFMA16 __builtin_amdgcn_mfma_f32_16x16x32_bf16

__device__ __forceinline__ unsigned short f2bf(float f) {
    union { float f; unsigned u; } v; v.f = f;
    return (unsigned short)((v.u + 0x7FFFu + ((v.u >> 16) & 1u)) >> 16);  // RNE
}
__device__ __forceinline__ unsigned short bfc(float f) {
    __hip_bfloat16 h = __float2bfloat16(f);
    union { __hip_bfloat16 h; unsigned short u; } v; v.h = h;
    return v.u;
}

typedef __attribute__((address_space(1))) const unsigned int as1_cu32;
typedef __attribute__((address_space(3))) unsigned int as3_u32;
__device__ __forceinline__ void gload16(const void* g, void* l) {
    __builtin_amdgcn_global_load_lds((as1_cu32*)g, (as3_u32*)l, 16, 0, 0);
}

// ============ prepass: W (f32 [k][n] 512x512) -> Wt (bf16 [n][k]) ============
__global__ __launch_bounds__(256) void kprep(const float* __restrict__ Wq,
                                             const float* __restrict__ Wk,
                                             const float* __restrict__ Wv,
                                             const float* __restrict__ Wo,
                                             unsigned short* __restrict__ Wt) {
    const float* src = blockIdx.z == 0 ? Wq : blockIdx.z == 1 ? Wk
                     : blockIdx.z == 2 ? Wv : Wo;
    unsigned short* dst = Wt + (size_t)blockIdx.z * DM * DM;
    __shared__ float t[64][65];
    int c = threadIdx.x & 63, r4 = threadIdx.x >> 6;
    int kb = blockIdx.x * 64, nb = blockIdx.y * 64;
    for (int i = 0; i < 16; i++) {
        int r = r4 * 16 + i;
        t[r][c] = src[(size_t)(kb + r) * DM + nb + c];
    }
    __syncthreads();
    for (int i = 0; i < 16; i++) {
        int r = r4 * 16 + i;
        dst[(size_t)(nb + r) * DM + kb + c] = f2bf(t[c][r]);
    }
}

// ============ kernel 1: fused pad+cvt+QKV projection =========================
// BM=64, BN=512 (A read ONCE), BK=64, 512 threads = 8 waves (1x8).
// A: 2-deep register prefetch (T14) -> cvt -> swizzled ds_write (8 KB LDS).
// B: gload_lds (64 KB). Raw s_barrier + counted vmcnt keeps A prefetch alive.
// Q/K out: [h*B+b][p][64]; V out transposed: VT[h*B+b][d][p].
__global__ __launch_bounds__(512, 4) void kproj(const float* __restrict__ q,
                                                const float* __restrict__ k,
                                                const float* __restrict__ v,
                                                const unsigned short* __restrict__ Wt,
                                                const float* __restrict__ bq,
                                                const float* __restrict__ bk,
                                                const float* __restrict__ bv,
                                                unsigned short* __restrict__ Qb,
                                                unsigned short* __restrict__ Kb,
                                                unsigned short* __restrict__ VT) {
    int mt = blockIdx.x, z = blockIdx.y;
    int ten = z >> 2, b = z & 3;
    const float* A = (ten == 0 ? q : ten == 1 ? k : v) + (size_t)b * SEQ * DM;
    const unsigned short* W = Wt + (size_t)ten * DM * DM;
    const float* bias = ten == 0 ? bq : ten == 1 ? bk : bv;
    float scale = ten == 0 ? 0.07715167498104595f : 1.f;   // 1/sqrt(168)
    int m0 = mt * 64;

    // Al [0,8192) bf16 [64][64] swz; Bl [8192,73728) bf16 [512][64] swz.
    // Epilogue bounce Ol [64][520] u16 = 66,560 B reuses whole block.
    __shared__ __align__(16) char lds[73728];
    char* Al = lds;
    char* Bl = lds + 8192;

    int tid = threadIdx.x, lane = tid & 63, w = tid >> 6;
    int wn = w * 64;
    int l15 = lane & 15, g = lane >> 4;

    // A-stage: thread covers row ar=tid>>3, chunk acx=tid&7 (8 f32)
    int ar = tid >> 3, acx = tid & 7;
    int p_ = m0 + ar;
    int arow = p_ - PAD_; arow = arow < 0 ? 0 : (arow > SEQ - 1 ? SEQ - 1 : arow);
    const float* asrc = A + (size_t)arow * DM + acx * 8;
    char* adst = Al + ar * 128 + ((acx ^ (ar & 7)) << 4);

    float4v acc[4][4];
#pragma unroll
    for (int i = 0; i < 4; i++)
#pragma unroll
        for (int j = 0; j < 4; j++) { float4v zz = {0.f,0.f,0.f,0.f}; acc[i][j] = zz; }

    // ---- A 2-deep register prefetch: apf[slot][half], slot = kt&1
    float4v apf[2][2];
    apf[0][0] = *(const float4v*)(asrc);
    apf[0][1] = *(const float4v*)(asrc + 4);
    apf[1][0] = *(const float4v*)(asrc + 64);
    apf[1][1] = *(const float4v*)(asrc + 64 + 4);

#pragma unroll
    for (int kt = 0; kt < 8; kt++) {
        const int slot = kt & 1;
        // --- cvt A(kt) (loaded 2 steps ago) -> one swizzled ds_write_b128
        {
            float4v f0 = apf[slot][0];
            float4v f1 = apf[slot][1];
            short8 h0;
            h0[0] = (short)bfc(f0.x); h0[1] = (short)bfc(f0.y);
            h0[2] = (short)bfc(f0.z); h0[3] = (short)bfc(f0.w);
            h0[4] = (short)bfc(f1.x); h0[5] = (short)bfc(f1.y);
            h0[6] = (short)bfc(f1.z); h0[7] = (short)bfc(f1.w);
            *(short8*)(adst) = h0;
        }
        // --- B: 512 rows x 8 chunks via gload_lds, pre-swizzled source
#pragma unroll
        for (int it = 0; it < 8; it++) {
            int c = it * 512 + tid;
            int r = c >> 3;
            int kg = (c & 7) ^ (r & 7);
            gload16(W + (size_t)r * DM + kt * 64 + kg * 8, Bl + c * 16);
        }
        __builtin_amdgcn_sched_barrier(0);
        // --- issue A(kt+2) AFTER B so counted vmcnt leaves only it in flight
        if (kt < 6) {
            apf[slot][0] = *(const float4v*)(asrc + (kt + 2) * 64);
            apf[slot][1] = *(const float4v*)(asrc + (kt + 2) * 64 + 4);
        }
        __builtin_amdgcn_sched_barrier(0);
        if (kt < 6) asm volatile("s_waitcnt vmcnt(2) lgkmcnt(0)" ::: "memory");
        else        asm volatile("s_waitcnt vmcnt(0) lgkmcnt(0)" ::: "memory");
        __builtin_amdgcn_s_barrier();
        __builtin_amdgcn_sched_barrier(0);
#pragma unroll
        for (int ks = 0; ks < 2; ks++) {
            short8 af[4], bfr[4];
#pragma unroll
            for (int i = 0; i < 4; i++) {
                int r = i * 16 + l15, kg = ks * 4 + g;
                af[i] = *(const short8*)(Al + r * 128 + ((kg ^ (r & 7)) << 4));
            }
#pragma unroll
            for (int j = 0; j < 4; j++) {
                int r = wn + j * 16 + l15, kg = ks * 4 + g;
                bfr[j] = *(const short8*)(Bl + r * 128 + ((kg ^ (r & 7)) << 4));
            }
#pragma unroll
            for (int i = 0; i < 4; i++)
#pragma unroll
                for (int j = 0; j < 4; j++)
                    acc[i][j] = MFMA16(af[i], bfr[j], acc[i][j], 0, 0, 0);
        }
        __builtin_amdgcn_s_barrier();
        __builtin_amdgcn_sched_barrier(0);
    }

    if (ten <= 1) {
        // bounce [64][520] u16 then coalesced short8 head-split writes
        unsigned short* Ol = (unsigned short*)lds;
#pragma unroll
        for (int j = 0; j < 4; j++) {
            int n = wn + j * 16 + l15;
            float bval = bias[n];
#pragma unroll
            for (int i = 0; i < 4; i++) {
                float4v vv = acc[i][j];
#pragma unroll
                for (int r = 0; r < 4; r++)
                    Ol[(i * 16 + g * 4 + r) * 520 + n] = f2bf((vv[r] + bval) * scale);
            }
        }
        __syncthreads();
        unsigned short* O = ten == 0 ? Qb : Kb;
        for (int c = tid; c < 4096; c += 512) {        // 64 rows x 64 chunks
            int row = c >> 6, n8 = c & 63;
            int p = m0 + row;
            if (p < KP) {
                int h = n8 >> 3, ch = n8 & 7;
                *(short8*)(O + ((size_t)(h * BATCH + b) * KP + p) * 64 + ch * 8) =
                    *(const short8*)(Ol + row * 520 + n8 * 8);
            }
        }
    } else {
        // V: direct transposed stores VT[hb][d][p] (lane has 4 consecutive p)
#pragma unroll
        for (int j = 0; j < 4; j++) {
            int n = wn + j * 16 + l15;
            float bval = bias[n];
            int h = n >> 6, d = n & 63;
            unsigned short* base = VT + ((size_t)(h * BATCH + b) * 64 + d) * KP;
#pragma unroll
            for (int i = 0; i < 4; i++) {
                int p = m0 + i * 16 + g * 4;
                if (p <= KP - 4) {
                    float4v vv = acc[i][j];
                    ushort4v wv;
                    wv[0] = f2bf(vv.x + bval); wv[1] = f2bf(vv.y + bval);
                    wv[2] = f2bf(vv.z + bval); wv[3] = f2bf(vv.w + bval);
                    *(ushort4v*)(base + p) = wv;
                }
            }
        }
    }
}

// ============ kernel 2: windowed causal attention ============================
__global__ __launch_bounds__(384) void kattn(const unsigned short* __restrict__ Qb,
                                             const unsigned short* __restrict__ Kb,
                                             const unsigned short* __restrict__ VT,
                                             unsigned short* __restrict__ attn) {
    int win = blockIdx.x, hb = blockIdx.y;
    int h = hb >> 2, b = hb & 3;
    const unsigned short* Qg = Qb + (size_t)hb * KP * 64;
    const unsigned short* Kg = Kb + (size_t)hb * KP * 64;
    const unsigned short* Vt = VT + (size_t)hb * 64 * KP;
    int p0 = win * STEP_;

    // Ql [0,12288) 96x64; Kl [12288,28672) 128x64; Vl [28672,45056) 64x128;
    // Pl [45056,69632) 96x128. Ol reuses Ql.
    __shared__ __align__(16) char lds[69632];

    int tid = threadIdx.x, lane = tid & 63, f = tid >> 6;
    int l15 = lane & 15, g = lane >> 4;

#pragma unroll
    for (int it = 0; it < 5; it++) {
        int base = it * 384 + f * 64;
        if (base < 768) {                       // Q chunks
            int c = base + lane;
            int qi = c >> 3, kg = (c & 7) ^ (qi & 7);
            gload16(Qg + (size_t)(p0 + PAD_ + qi) * 64 + kg * 8, lds + base * 16);
        } else if (base < 1792) {               // K chunks
            int c = base + lane - 768;
            int x = c >> 3, kg = (c & 7) ^ (x & 7);
            gload16(Kg + (size_t)(p0 + x) * 64 + kg * 8, lds + base * 16);
        }
    }
    for (int c = tid; c < 2048; c += 384) {
        int d = c >> 5, c2 = c & 31;
        ushort4v wv = *(const ushort4v*)(Vt + (size_t)d * KP + p0 + c2 * 4);
        int cx = c2 >> 1;
        *(ushort4v*)(lds + 28672 + d * 256 + (((cx ^ (d & 7)) << 4) | ((c2 & 1) * 8))) = wv;
    }
    __syncthreads();

    short8 bq2[2];
    {
        int r = f * 16 + l15;
#pragma unroll
        for (int ks = 0; ks < 2; ks++) {
            int kg = ks * 4 + g;
            bq2[ks] = *(const short8*)(lds + r * 128 + ((kg ^ (r & 7)) << 4));
        }
    }
    float4v st[8];
#pragma unroll
    for (int xf = 0; xf < 8; xf++) {
        float4v zz = {0.f,0.f,0.f,0.f}; st[xf] = zz;
#pragma unroll
        for (int ks = 0; ks < 2; ks++) {
            int r = xf * 16 + l15;
            int kg = ks * 4 + g;
            short8 a = *(const short8*)(lds + 12288 + r * 128 + ((kg ^ (r & 7)) << 4));
            st[xf] = MFMA16(a, bq2[ks], st[xf], 0, 0, 0);
        }
    }

    int w_abs = PAD_ + f * 16 + l15;
    int w_eff = w_abs > 125 ? 125 : w_abs;
    float mx = -1e30f;
#pragma unroll
    for (int xf = 0; xf < 8; xf++)
#pragma unroll
        for (int r = 0; r < 4; r++) {
            int x = xf * 16 + g * 4 + r;
            float vv = st[xf][r];
            if (x > w_eff) vv = -1e30f;
            st[xf][r] = vv;
            mx = fmaxf(mx, vv);
        }
    mx = fmaxf(mx, __shfl_xor(mx, 16));
    mx = fmaxf(mx, __shfl_xor(mx, 32));
    float s = 0.f;
#pragma unroll
    for (int xf = 0; xf < 8; xf++)
#pragma unroll
        for (int r = 0; r < 4; r++) {
            float e = __expf(st[xf][r] - mx);
            st[xf][r] = e;
            s += e;
        }
    s += __shfl_xor(s, 16);
    s += __shfl_xor(s, 32);
    float inv = 1.f / s;

    {
        int qi = f * 16 + l15;
#pragma unroll
        for (int xf = 0; xf < 8; xf++) {
            ushort4v pw;
#pragma unroll
            for (int r = 0; r < 4; r++) pw[r] = f2bf(st[xf][r] * inv);
            int xc = 2 * xf + (g >> 1);
            *(ushort4v*)(lds + 45056 + qi * 256 + ((xc ^ (qi & 7)) << 4) + (g & 1) * 8) = pw;
        }
    }
    __syncthreads();

    float4v pv[4];
#pragma unroll
    for (int j = 0; j < 4; j++) { float4v zz = {0.f,0.f,0.f,0.f}; pv[j] = zz; }
    int qi = f * 16 + l15;
#pragma unroll
    for (int g2 = 0; g2 < 4; g2++) {
        int xc = g2 * 4 + g;
        short8 a = *(const short8*)(lds + 45056 + qi * 256 + ((xc ^ (qi & 7)) << 4));
#pragma unroll
        for (int j = 0; j < 4; j++) {
            int d = j * 16 + l15;
            short8 bvv = *(const short8*)(lds + 28672 + d * 256 + ((xc ^ (d & 7)) << 4));
            pv[j] = MFMA16(a, bvv, pv[j], 0, 0, 0);
        }
    }

    unsigned short* Ol = (unsigned short*)lds;
#pragma unroll
    for (int j = 0; j < 4; j++) {
        int d = j * 16 + l15;
#pragma unroll
        for (int r = 0; r < 4; r++) {
            int qq = f * 16 + g * 4 + r;
            int byte = qq * 128 + ((((d >> 3) ^ (qq & 7))) << 4) + (d & 7) * 2;
            *(unsigned short*)((char*)Ol + byte) = f2bf(pv[j][r]);
        }
    }
    __syncthreads();
    for (int c = tid; c < 672; c += 384) {
        int qq = c >> 3, ch = c & 7;
        short8 hv = *(const short8*)((char*)Ol + qq * 128 + ((ch ^ (qq & 7)) << 4));
        size_t off = ((size_t)(b * SEQ + win * STEP_ + qq) * DM) + h * 64 + ch * 8;
        *(short8*)(attn + off) = hv;
    }
}

// ============ kernel 3: output projection, m97 128x128x64 ====================
__global__ __launch_bounds__(256) void kout(const unsigned short* __restrict__ Ab,
                                            const unsigned short* __restrict__ W,
                                            const float* __restrict__ bias,
                                            float* __restrict__ Out) {
    int m0 = blockIdx.x * 128, n0 = blockIdx.y * 128;
    __shared__ __align__(16) char lds[32768];
    char* Al = lds;
    char* Bl = lds + 16384;
    int tid = threadIdx.x, lane = tid & 63, w = tid >> 6;
    int wm = (w >> 1) * 64, wn = (w & 1) * 64;
    int l15 = lane & 15, g = lane >> 4;

    float4v acc[4][4];
#pragma unroll
    for (int i = 0; i < 4; i++)
#pragma unroll
        for (int j = 0; j < 4; j++) { float4v zz = {0.f,0.f,0.f,0.f}; acc[i][j] = zz; }

    for (int kt = 0; kt < 8; kt++) {
#pragma unroll
        for (int it = 0; it < 4; it++) {
            int c = it * 256 + tid;
            int r = c >> 3;
            int kg = (c & 7) ^ (r & 7);
            int row = m0 + r; if (row > MROWS - 1) row = MROWS - 1;
            gload16(Ab + (size_t)row * DM + kt * 64 + kg * 8, Al + c * 16);
        }
#pragma unroll
        for (int it = 0; it < 4; it++) {
            int c = it * 256 + tid;
            int r = c >> 3;
            int kg = (c & 7) ^ (r & 7);
            gload16(W + (size_t)(n0 + r) * DM + kt * 64 + kg * 8, Bl + c * 16);
        }
        __syncthreads();
#pragma unroll
        for (int ks = 0; ks < 2; ks++) {
            short8 af[4], bfr[4];
#pragma unroll
            for (int i = 0; i < 4; i++) {
                int r = wm + i * 16 + l15, kg = ks * 4 + g;
                af[i] = *(const short8*)(Al + r * 128 + ((kg ^ (r & 7)) << 4));
            }
#pragma unroll
            for (int j = 0; j < 4; j++) {
                int r = wn + j * 16 + l15, kg = ks * 4 + g;
                bfr[j] = *(const short8*)(Bl + r * 128 + ((kg ^ (r & 7)) << 4));
            }
#pragma unroll
            for (int i = 0; i < 4; i++)
#pragma unroll
                for (int j = 0; j < 4; j++)
                    acc[i][j] = MFMA16(af[i], bfr[j], acc[i][j], 0, 0, 0);
        }
        __syncthreads();
    }
#pragma unroll
    for (int j = 0; j < 4; j++) {
        int n = n0 + wn + j * 16 + l15;
        float bv = bias[n];
#pragma unroll
        for (int i = 0; i < 4; i++) {
            float4v vv = acc[i][j];
#pragma unroll
            for (int r = 0; r < 4; r++) {
                int m = m0 + wm + i * 16 + g * 4 + r;
                if (m < MROWS) Out[(size_t)m * DM + n] = vv[r] + bv;
            }
        }
    }
}

// ============ launch =========================================================
extern "C" void kernel_launch(void* const* d_in, const int* in_sizes, int n_in,
                              void* d_out, int out_size, void* d_ws, size_t ws_size,
                              hipStream_t stream) {
    const float* q  = (const float*)d_in[0];
    const float* k  = (const float*)d_in[1];
    const float* v  = (const float*)d_in[2];
    const float* Wq = (const float*)d_in[3];
    const float* bq = (const float*)d_in[4];
    const float* Wk = (const float*)d_in[5];
    const float* bk = (const float*)d_in[6];
    const float* Wv = (const float*)d_in[7];
    const float* bv = (const float*)d_in[8];
    const float* Wo = (const float*)d_in[9];
    const float* bo = (const float*)d_in[10];

    const size_t WT_ELEMS  = (size_t)4 * DM * DM;
    const size_t QKV_ELEMS = (size_t)32 * KP * 64;
    const size_t ATT_ELEMS = (size_t)MROWS * DM;
    size_t need = (WT_ELEMS + 3 * QKV_ELEMS + ATT_ELEMS) * 2;
    if (ws_size < need) return;

    unsigned short* Wt = (unsigned short*)d_ws;
    unsigned short* Qb = Wt + WT_ELEMS;
    unsigned short* Kb = Qb + QKV_ELEMS;
    unsigned short* VT = Kb + QKV_ELEMS;
    unsigned short* Ab = VT + QKV_ELEMS;

    kprep<<<dim3(8, 8, 4), dim3(256), 0, stream>>>(Wq, Wk, Wv, Wo, Wt);
    kproj<<<dim3(133, 12), dim3(512), 0, stream>>>(q, k, v, Wt, bq, bk, bv,
                                                   Qb, Kb, VT);
    kattn<<<dim3(NWIN, 32), dim3(384), 0, stream>>>(Qb, Kb, VT, Ab);
    kout<<<dim3(263, 4), dim3(256), 0, stream>>>(Ab, Wt + 3 * DM * DM, bo,
                                                 (float*)d_out);
}

// Round 9
// 234.441 us; speedup vs baseline: 1.0790x; 1.0790x over previous
//
#include <hip/hip_runtime.h>
#include <hip/hip_bf16.h>
#include <stdint.h>

// ---- problem constants ----
#define BATCH 4
#define SEQ   8400
#define DM    512
#define KP    8484      // SEQ + 2*42 (edge pad)
#define NWIN  100
#define STEP_ 84
#define PAD_  42
#define NKEY  126
#define MROWS 33600     // BATCH*SEQ
#define NTILES 266      // ceil(KP/32)
#define TPB   13        // tiles per block (21 blocks * 13 >= 266)
#define NBI   21

typedef __attribute__((ext_vector_type(8))) short short8;
typedef __attribute__((ext_vector_type(4))) float float4v;
typedef __attribute__((ext_vector_type(4))) unsigned short ushort4v;

#define MFMA16 __builtin_amdgcn_mfma_f32_16x16x32_bf16

__device__ __forceinline__ unsigned short f2bf(float f) {
    union { float f; unsigned u; } v; v.f = f;
    return (unsigned short)((v.u + 0x7FFFu + ((v.u >> 16) & 1u)) >> 16);  // RNE
}
__device__ __forceinline__ unsigned short bfc(float f) {
    __hip_bfloat16 h = __float2bfloat16(f);
    union { __hip_bfloat16 h; unsigned short u; } v; v.h = h;
    return v.u;
}

typedef __attribute__((address_space(1))) const unsigned int as1_cu32;
typedef __attribute__((address_space(3))) unsigned int as3_u32;
__device__ __forceinline__ void gload16(const void* g, void* l) {
    __builtin_amdgcn_global_load_lds((as1_cu32*)g, (as3_u32*)l, 16, 0, 0);
}

// ============ prepass: W (f32 [k][n] 512x512) -> Wt (bf16 [n][k]) ============
__global__ __launch_bounds__(256) void kprep(const float* __restrict__ Wq,
                                             const float* __restrict__ Wk,
                                             const float* __restrict__ Wv,
                                             const float* __restrict__ Wo,
                                             unsigned short* __restrict__ Wt) {
    const float* src = blockIdx.z == 0 ? Wq : blockIdx.z == 1 ? Wk
                     : blockIdx.z == 2 ? Wv : Wo;
    unsigned short* dst = Wt + (size_t)blockIdx.z * DM * DM;
    __shared__ float t[64][65];
    int c = threadIdx.x & 63, r4 = threadIdx.x >> 6;
    int kb = blockIdx.x * 64, nb = blockIdx.y * 64;
    for (int i = 0; i < 16; i++) {
        int r = r4 * 16 + i;
        t[r][c] = src[(size_t)(kb + r) * DM + nb + c];
    }
    __syncthreads();
    for (int i = 0; i < 16; i++) {
        int r = r4 * 16 + i;
        dst[(size_t)(nb + r) * DM + kb + c] = f2bf(t[c][r]);
    }
}

// ============ kernel 1: weight-stationary fused pad+cvt+QKV projection =======
// 512 thr = 8 waves; wave holds B[32 n][512 k] bf16 in 128 VGPRs (loaded once).
// Block covers 256 n (one n-half); A tile [32 m][512 k] streamed via LDS
// (single 32 KB buffer; write->bar1->read->bar2 makes it safe). Next tile's
// A global loads issued before bar1 so latency hides under MFMA+epilogue.
// Grid pairing: the two n-halves of a work unit are 8 blockIdx apart (same XCD
// under round-robin) so the 2nd A read L2-hits.
// Q/K out: [h*B+b][p][64]; V out transposed: VT[h*B+b][d][p].
__global__ __launch_bounds__(512, 2) void kproj(const float* __restrict__ q,
                                                const float* __restrict__ k,
                                                const float* __restrict__ v,
                                                const unsigned short* __restrict__ Wt,
                                                const float* __restrict__ bq,
                                                const float* __restrict__ bk,
                                                const float* __restrict__ bv,
                                                unsigned short* __restrict__ Qb,
                                                unsigned short* __restrict__ Kb,
                                                unsigned short* __restrict__ VT) {
    // decode: pair L and L+8 share work unit P, differ in n-half
    int L = blockIdx.x;                          // 0..511
    int P = (L >> 4) * 8 + (L & 7);              // work unit 0..255
    int nhalf = (L >> 3) & 1;
    if (P >= 12 * NBI) return;
    int z = P / NBI, bi = P % NBI;
    int ten = z >> 2, b = z & 3;
    int t0 = bi * TPB;
    int tcnt = NTILES - t0; if (tcnt > TPB) tcnt = TPB;
    if (tcnt <= 0) return;

    const float* A = (ten == 0 ? q : ten == 1 ? k : v) + (size_t)b * SEQ * DM;
    const unsigned short* Wten = Wt + (size_t)ten * DM * DM;
    const float* bias = ten == 0 ? bq : ten == 1 ? bk : bv;
    float scale = ten == 0 ? 0.07715167498104595f : 1.f;   // 1/sqrt(168)

    __shared__ __align__(16) char lds[32768];    // [32 rows][1024 B] bf16 swz

    int tid = threadIdx.x, lane = tid & 63, w = tid >> 6;
    int l15 = lane & 15, g = lane >> 4;
    int n0w = nhalf * 256 + w * 32;              // wave's 32-col slice
    int h = n0w >> 6;
    int hb2 = h * BATCH + b;

    // ---- B slice into registers (once per block): Breg[nf][s] = 8 k-elems
    short8 Breg[2][16];
#pragma unroll
    for (int nf = 0; nf < 2; nf++)
#pragma unroll
        for (int s5 = 0; s5 < 16; s5++)
            Breg[nf][s5] = *(const short8*)(Wten +
                (size_t)(n0w + nf * 16 + l15) * DM + s5 * 32 + g * 8);

    float bias0 = bias[n0w + l15];
    float bias1 = bias[n0w + 16 + l15];

    // A staging: thread covers row srow (0..31), chunks sc, sc+16, sc+32, sc+48
    int srow = tid >> 4, sc = tid & 15;
    int woff = srow * 1024 + ((sc ^ (srow & 7)) << 4);

    auto loadreg = [&](float4v (&d)[8], int tt) {
        int p = tt * 32 + srow; if (p > KP - 1) p = KP - 1;
        int ar = p - PAD_; ar = ar < 0 ? 0 : (ar > SEQ - 1 ? SEQ - 1 : ar);
        const float* s = A + (size_t)ar * DM + sc * 8;
#pragma unroll
        for (int j = 0; j < 4; j++) {
            d[2 * j]     = *(const float4v*)(s + j * 128);
            d[2 * j + 1] = *(const float4v*)(s + j * 128 + 4);
        }
    };

    float4v a[8];
    loadreg(a, t0);

    for (int ti = 0; ti < tcnt; ti++) {
        int tt = t0 + ti;
        // ---- cvt + 4 swizzled ds_write_b128 (full 32-row tile across block)
#pragma unroll
        for (int j = 0; j < 4; j++) {
            float4v f0 = a[2 * j], f1 = a[2 * j + 1];
            short8 h0;
            h0[0] = (short)bfc(f0.x); h0[1] = (short)bfc(f0.y);
            h0[2] = (short)bfc(f0.z); h0[3] = (short)bfc(f0.w);
            h0[4] = (short)bfc(f1.x); h0[5] = (short)bfc(f1.y);
            h0[6] = (short)bfc(f1.z); h0[7] = (short)bfc(f1.w);
            *(short8*)(lds + woff + j * 256) = h0;
        }
        // ---- issue next tile's A loads (hide under MFMA + epilogue)
        if (ti + 1 < tcnt) loadreg(a, tt + 1);
        __builtin_amdgcn_sched_barrier(0);
        asm volatile("s_waitcnt lgkmcnt(0)" ::: "memory");
        __builtin_amdgcn_s_barrier();
        __builtin_amdgcn_sched_barrier(0);

        float4v acc[2][2];
#pragma unroll
        for (int mf = 0; mf < 2; mf++)
#pragma unroll
            for (int nf = 0; nf < 2; nf++) {
                float4v zz = {0.f, 0.f, 0.f, 0.f}; acc[mf][nf] = zz;
            }
#pragma unroll
        for (int s5 = 0; s5 < 16; s5++) {
            short8 afr[2];
#pragma unroll
            for (int mf = 0; mf < 2; mf++) {
                int row = mf * 16 + l15, c = s5 * 4 + g;
                afr[mf] = *(const short8*)(lds + row * 1024 + ((c ^ (row & 7)) << 4));
            }
#pragma unroll
            for (int mf = 0; mf < 2; mf++)
#pragma unroll
                for (int nf = 0; nf < 2; nf++)
                    acc[mf][nf] = MFMA16(afr[mf], Breg[nf][s5], acc[mf][nf], 0, 0, 0);
        }
        __builtin_amdgcn_s_barrier();            // all reads done -> buf reusable
        __builtin_amdgcn_sched_barrier(0);

        // ---- epilogue for this tile
        int p0 = tt * 32;
        if (ten <= 1) {
            unsigned short* O = ten == 0 ? Qb : Kb;
#pragma unroll
            for (int nf = 0; nf < 2; nf++) {
                float bval = nf ? bias1 : bias0;
                int d = ((n0w + nf * 16) & 63) + l15;
                unsigned short* op = O + (size_t)hb2 * KP * 64 + d;
#pragma unroll
                for (int mf = 0; mf < 2; mf++) {
                    float4v vv = acc[mf][nf];
#pragma unroll
                    for (int r = 0; r < 4; r++) {
                        int p = p0 + mf * 16 + g * 4 + r;
                        if (p < KP)
                            op[(size_t)p * 64] = f2bf((vv[r] + bval) * scale);
                    }
                }
            }
        } else {
#pragma unroll
            for (int nf = 0; nf < 2; nf++) {
                float bval = nf ? bias1 : bias0;
                int d = ((n0w + nf * 16) & 63) + l15;
                unsigned short* base = VT + ((size_t)hb2 * 64 + d) * KP;
#pragma unroll
                for (int mf = 0; mf < 2; mf++) {
                    int p = p0 + mf * 16 + g * 4;
                    if (p <= KP - 4) {
                        float4v vv = acc[mf][nf];
                        ushort4v wv;
                        wv[0] = f2bf(vv.x + bval); wv[1] = f2bf(vv.y + bval);
                        wv[2] = f2bf(vv.z + bval); wv[3] = f2bf(vv.w + bval);
                        *(ushort4v*)(base + p) = wv;
                    }
                }
            }
        }
    }
}

// ============ kernel 2: windowed causal attention ============================
__global__ __launch_bounds__(384) void kattn(const unsigned short* __restrict__ Qb,
                                             const unsigned short* __restrict__ Kb,
                                             const unsigned short* __restrict__ VT,
                                             unsigned short* __restrict__ attn) {
    int win = blockIdx.x, hb = blockIdx.y;
    int h = hb >> 2, b = hb & 3;
    const unsigned short* Qg = Qb + (size_t)hb * KP * 64;
    const unsigned short* Kg = Kb + (size_t)hb * KP * 64;
    const unsigned short* Vt = VT + (size_t)hb * 64 * KP;
    int p0 = win * STEP_;

    // Ql [0,12288) 96x64; Kl [12288,28672) 128x64; Vl [28672,45056) 64x128;
    // Pl [45056,69632) 96x128. Ol reuses Ql.
    __shared__ __align__(16) char lds[69632];

    int tid = threadIdx.x, lane = tid & 63, f = tid >> 6;
    int l15 = lane & 15, g = lane >> 4;

#pragma unroll
    for (int it = 0; it < 5; it++) {
        int base = it * 384 + f * 64;
        if (base < 768) {                       // Q chunks
            int c = base + lane;
            int qi = c >> 3, kg = (c & 7) ^ (qi & 7);
            gload16(Qg + (size_t)(p0 + PAD_ + qi) * 64 + kg * 8, lds + base * 16);
        } else if (base < 1792) {               // K chunks
            int c = base + lane - 768;
            int x = c >> 3, kg = (c & 7) ^ (x & 7);
            gload16(Kg + (size_t)(p0 + x) * 64 + kg * 8, lds + base * 16);
        }
    }
    for (int c = tid; c < 2048; c += 384) {
        int d = c >> 5, c2 = c & 31;
        ushort4v wv = *(const ushort4v*)(Vt + (size_t)d * KP + p0 + c2 * 4);
        int cx = c2 >> 1;
        *(ushort4v*)(lds + 28672 + d * 256 + (((cx ^ (d & 7)) << 4) | ((c2 & 1) * 8))) = wv;
    }
    __syncthreads();

    short8 bq2[2];
    {
        int r = f * 16 + l15;
#pragma unroll
        for (int ks = 0; ks < 2; ks++) {
            int kg = ks * 4 + g;
            bq2[ks] = *(const short8*)(lds + r * 128 + ((kg ^ (r & 7)) << 4));
        }
    }
    float4v st[8];
#pragma unroll
    for (int xf = 0; xf < 8; xf++) {
        float4v zz = {0.f,0.f,0.f,0.f}; st[xf] = zz;
#pragma unroll
        for (int ks = 0; ks < 2; ks++) {
            int r = xf * 16 + l15;
            int kg = ks * 4 + g;
            short8 a = *(const short8*)(lds + 12288 + r * 128 + ((kg ^ (r & 7)) << 4));
            st[xf] = MFMA16(a, bq2[ks], st[xf], 0, 0, 0);
        }
    }

    int w_abs = PAD_ + f * 16 + l15;
    int w_eff = w_abs > 125 ? 125 : w_abs;
    float mx = -1e30f;
#pragma unroll
    for (int xf = 0; xf < 8; xf++)
#pragma unroll
        for (int r = 0; r < 4; r++) {
            int x = xf * 16 + g * 4 + r;
            float vv = st[xf][r];
            if (x > w_eff) vv = -1e30f;
            st[xf][r] = vv;
            mx = fmaxf(mx, vv);
        }
    mx = fmaxf(mx, __shfl_xor(mx, 16));
    mx = fmaxf(mx, __shfl_xor(mx, 32));
    float s = 0.f;
#pragma unroll
    for (int xf = 0; xf < 8; xf++)
#pragma unroll
        for (int r = 0; r < 4; r++) {
            float e = __expf(st[xf][r] - mx);
            st[xf][r] = e;
            s += e;
        }
    s += __shfl_xor(s, 16);
    s += __shfl_xor(s, 32);
    float inv = 1.f / s;

    {
        int qi = f * 16 + l15;
#pragma unroll
        for (int xf = 0; xf < 8; xf++) {
            ushort4v pw;
#pragma unroll
            for (int r = 0; r < 4; r++) pw[r] = f2bf(st[xf][r] * inv);
            int xc = 2 * xf + (g >> 1);
            *(ushort4v*)(lds + 45056 + qi * 256 + ((xc ^ (qi & 7)) << 4) + (g & 1) * 8) = pw;
        }
    }
    __syncthreads();

    float4v pv[4];
#pragma unroll
    for (int j = 0; j < 4; j++) { float4v zz = {0.f,0.f,0.f,0.f}; pv[j] = zz; }
    int qi = f * 16 + l15;
#pragma unroll
    for (int g2 = 0; g2 < 4; g2++) {
        int xc = g2 * 4 + g;
        short8 a = *(const short8*)(lds + 45056 + qi * 256 + ((xc ^ (qi & 7)) << 4));
#pragma unroll
        for (int j = 0; j < 4; j++) {
            int d = j * 16 + l15;
            short8 bvv = *(const short8*)(lds + 28672 + d * 256 + ((xc ^ (d & 7)) << 4));
            pv[j] = MFMA16(a, bvv, pv[j], 0, 0, 0);
        }
    }

    unsigned short* Ol = (unsigned short*)lds;
#pragma unroll
    for (int j = 0; j < 4; j++) {
        int d = j * 16 + l15;
#pragma unroll
        for (int r = 0; r < 4; r++) {
            int qq = f * 16 + g * 4 + r;
            int byte = qq * 128 + ((((d >> 3) ^ (qq & 7))) << 4) + (d & 7) * 2;
            *(unsigned short*)((char*)Ol + byte) = f2bf(pv[j][r]);
        }
    }
    __syncthreads();
    for (int c = tid; c < 672; c += 384) {
        int qq = c >> 3, ch = c & 7;
        short8 hv = *(const short8*)((char*)Ol + qq * 128 + ((ch ^ (qq & 7)) << 4));
        size_t off = ((size_t)(b * SEQ + win * STEP_ + qq) * DM) + h * 64 + ch * 8;
        *(short8*)(attn + off) = hv;
    }
}

// ============ kernel 3: output projection, m97 128x128x64 ====================
__global__ __launch_bounds__(256) void kout(const unsigned short* __restrict__ Ab,
                                            const unsigned short* __restrict__ W,
                                            const float* __restrict__ bias,
                                            float* __restrict__ Out) {
    int m0 = blockIdx.x * 128, n0 = blockIdx.y * 128;
    __shared__ __align__(16) char lds[32768];
    char* Al = lds;
    char* Bl = lds + 16384;
    int tid = threadIdx.x, lane = tid & 63, w = tid >> 6;
    int wm = (w >> 1) * 64, wn = (w & 1) * 64;
    int l15 = lane & 15, g = lane >> 4;

    float4v acc[4][4];
#pragma unroll
    for (int i = 0; i < 4; i++)
#pragma unroll
        for (int j = 0; j < 4; j++) { float4v zz = {0.f,0.f,0.f,0.f}; acc[i][j] = zz; }

    for (int kt = 0; kt < 8; kt++) {
#pragma unroll
        for (int it = 0; it < 4; it++) {
            int c = it * 256 + tid;
            int r = c >> 3;
            int kg = (c & 7) ^ (r & 7);
            int row = m0 + r; if (row > MROWS - 1) row = MROWS - 1;
            gload16(Ab + (size_t)row * DM + kt * 64 + kg * 8, Al + c * 16);
        }
#pragma unroll
        for (int it = 0; it < 4; it++) {
            int c = it * 256 + tid;
            int r = c >> 3;
            int kg = (c & 7) ^ (r & 7);
            gload16(W + (size_t)(n0 + r) * DM + kt * 64 + kg * 8, Bl + c * 16);
        }
        __syncthreads();
#pragma unroll
        for (int ks = 0; ks < 2; ks++) {
            short8 af[4], bfr[4];
#pragma unroll
            for (int i = 0; i < 4; i++) {
                int r = wm + i * 16 + l15, kg = ks * 4 + g;
                af[i] = *(const short8*)(Al + r * 128 + ((kg ^ (r & 7)) << 4));
            }
#pragma unroll
            for (int j = 0; j < 4; j++) {
                int r = wn + j * 16 + l15, kg = ks * 4 + g;
                bfr[j] = *(const short8*)(Bl + r * 128 + ((kg ^ (r & 7)) << 4));
            }
#pragma unroll
            for (int i = 0; i < 4; i++)
#pragma unroll
                for (int j = 0; j < 4; j++)
                    acc[i][j] = MFMA16(af[i], bfr[j], acc[i][j], 0, 0, 0);
        }
        __syncthreads();
    }
#pragma unroll
    for (int j = 0; j < 4; j++) {
        int n = n0 + wn + j * 16 + l15;
        float bv = bias[n];
#pragma unroll
        for (int i = 0; i < 4; i++) {
            float4v vv = acc[i][j];
#pragma unroll
            for (int r = 0; r < 4; r++) {
                int m = m0 + wm + i * 16 + g * 4 + r;
                if (m < MROWS) Out[(size_t)m * DM + n] = vv[r] + bv;
            }
        }
    }
}

// ============ launch =========================================================
extern "C" void kernel_launch(void* const* d_in, const int* in_sizes, int n_in,
                              void* d_out, int out_size, void* d_ws, size_t ws_size,
                              hipStream_t stream) {
    const float* q  = (const float*)d_in[0];
    const float* k  = (const float*)d_in[1];
    const float* v  = (const float*)d_in[2];
    const float* Wq = (const float*)d_in[3];
    const float* bq = (const float*)d_in[4];
    const float* Wk = (const float*)d_in[5];
    const float* bk = (const float*)d_in[6];
    const float* Wv = (const float*)d_in[7];
    const float* bv = (const float*)d_in[8];
    const float* Wo = (const float*)d_in[9];
    const float* bo = (const float*)d_in[10];

    const size_t WT_ELEMS  = (size_t)4 * DM * DM;
    const size_t QKV_ELEMS = (size_t)32 * KP * 64;
    const size_t ATT_ELEMS = (size_t)MROWS * DM;
    size_t need = (WT_ELEMS + 3 * QKV_ELEMS + ATT_ELEMS) * 2;
    if (ws_size < need) return;

    unsigned short* Wt = (unsigned short*)d_ws;
    unsigned short* Qb = Wt + WT_ELEMS;
    unsigned short* Kb = Qb + QKV_ELEMS;
    unsigned short* VT = Kb + QKV_ELEMS;
    unsigned short* Ab = VT + QKV_ELEMS;

    kprep<<<dim3(8, 8, 4), dim3(256), 0, stream>>>(Wq, Wk, Wv, Wo, Wt);
    kproj<<<dim3(512), dim3(512), 0, stream>>>(q, k, v, Wt, bq, bk, bv,
                                               Qb, Kb, VT);
    kattn<<<dim3(NWIN, 32), dim3(384), 0, stream>>>(Qb, Kb, VT, Ab);
    kout<<<dim3(263, 4), dim3(256), 0, stream>>>(Ab, Wt + 3 * DM * DM, bo,
                                                 (float*)d_out);
}

// Round 10
// 229.270 us; speedup vs baseline: 1.1034x; 1.0226x over previous
//
#include <hip/hip_runtime.h>
#include <hip/hip_bf16.h>
#include <stdint.h>

// ---- problem constants ----
#define BATCH 4
#define SEQ   8400
#define DM    512
#define KP    8484      // SEQ + 2*42 (edge pad)
#define NWIN  100
#define STEP_ 84
#define PAD_  42
#define NKEY  126
#define MROWS 33600     // BATCH*SEQ
#define NTILES 266      // ceil(KP/32)
#define TPB   7         // tiles per work unit (42*7 >= 266)
#define NBI   42
#define OT_TPB 3        // kout tiles per work unit (350*3 = 1050 exact)
#define OT_NBI 350

typedef __attribute__((ext_vector_type(8))) short short8;
typedef __attribute__((ext_vector_type(4))) float float4v;
typedef __attribute__((ext_vector_type(4))) unsigned short ushort4v;

#define MFMA16 __builtin_amdgcn_mfma_f32_16x16x32_bf16

__device__ __forceinline__ unsigned short f2bf(float f) {
    union { float f; unsigned u; } v; v.f = f;
    return (unsigned short)((v.u + 0x7FFFu + ((v.u >> 16) & 1u)) >> 16);  // RNE
}
__device__ __forceinline__ unsigned short bfc(float f) {
    __hip_bfloat16 h = __float2bfloat16(f);
    union { __hip_bfloat16 h; unsigned short u; } v; v.h = h;
    return v.u;
}

typedef __attribute__((address_space(1))) const unsigned int as1_cu32;
typedef __attribute__((address_space(3))) unsigned int as3_u32;
__device__ __forceinline__ void gload16(const void* g, void* l) {
    __builtin_amdgcn_global_load_lds((as1_cu32*)g, (as3_u32*)l, 16, 0, 0);
}

// ============ prepass: W (f32 [k][n] 512x512) -> Wt (bf16 [n][k]) ============
__global__ __launch_bounds__(256) void kprep(const float* __restrict__ Wq,
                                             const float* __restrict__ Wk,
                                             const float* __restrict__ Wv,
                                             const float* __restrict__ Wo,
                                             unsigned short* __restrict__ Wt) {
    const float* src = blockIdx.z == 0 ? Wq : blockIdx.z == 1 ? Wk
                     : blockIdx.z == 2 ? Wv : Wo;
    unsigned short* dst = Wt + (size_t)blockIdx.z * DM * DM;
    __shared__ float t[64][65];
    int c = threadIdx.x & 63, r4 = threadIdx.x >> 6;
    int kb = blockIdx.x * 64, nb = blockIdx.y * 64;
    for (int i = 0; i < 16; i++) {
        int r = r4 * 16 + i;
        t[r][c] = src[(size_t)(kb + r) * DM + nb + c];
    }
    __syncthreads();
    for (int i = 0; i < 16; i++) {
        int r = r4 * 16 + i;
        dst[(size_t)(nb + r) * DM + kb + c] = f2bf(t[c][r]);
    }
}

// ============ kernel 1: weight-stationary fused pad+cvt+QKV projection =======
// 512 thr = 8 waves; wave holds B[32 n][512 k] bf16 in 128 VGPRs (loaded once).
// Block covers 256 n (one n-half); A tile [32 m][512 k] streamed via LDS
// (single 32 KB buffer). Next tile's A loads issued before bar1.
// Grid pairing: n-halves of a work unit are 8 blockIdx apart (same XCD).
__global__ __launch_bounds__(512, 2) void kproj(const float* __restrict__ q,
                                                const float* __restrict__ k,
                                                const float* __restrict__ v,
                                                const unsigned short* __restrict__ Wt,
                                                const float* __restrict__ bq,
                                                const float* __restrict__ bk,
                                                const float* __restrict__ bv,
                                                unsigned short* __restrict__ Qb,
                                                unsigned short* __restrict__ Kb,
                                                unsigned short* __restrict__ VT) {
    int L = blockIdx.x;                          // 0..1007
    int P = (L >> 4) * 8 + (L & 7);              // work unit
    int nhalf = (L >> 3) & 1;
    if (P >= 12 * NBI) return;
    int z = P / NBI, bi = P % NBI;
    int ten = z >> 2, b = z & 3;
    int t0 = bi * TPB;
    int tcnt = NTILES - t0; if (tcnt > TPB) tcnt = TPB;
    if (tcnt <= 0) return;

    const float* A = (ten == 0 ? q : ten == 1 ? k : v) + (size_t)b * SEQ * DM;
    const unsigned short* Wten = Wt + (size_t)ten * DM * DM;
    const float* bias = ten == 0 ? bq : ten == 1 ? bk : bv;
    float scale = ten == 0 ? 0.07715167498104595f : 1.f;   // 1/sqrt(168)

    __shared__ __align__(16) char lds[32768];    // [32 rows][1024 B] bf16 swz

    int tid = threadIdx.x, lane = tid & 63, w = tid >> 6;
    int l15 = lane & 15, g = lane >> 4;
    int n0w = nhalf * 256 + w * 32;              // wave's 32-col slice
    int h = n0w >> 6;
    int hb2 = h * BATCH + b;

    // ---- B slice into registers (once per block)
    short8 Breg[2][16];
#pragma unroll
    for (int nf = 0; nf < 2; nf++)
#pragma unroll
        for (int s5 = 0; s5 < 16; s5++)
            Breg[nf][s5] = *(const short8*)(Wten +
                (size_t)(n0w + nf * 16 + l15) * DM + s5 * 32 + g * 8);

    float bias0 = bias[n0w + l15];
    float bias1 = bias[n0w + 16 + l15];

    // A staging: thread covers row srow (0..31), chunks sc, sc+16, sc+32, sc+48
    int srow = tid >> 4, sc = tid & 15;
    int woff = srow * 1024 + ((sc ^ (srow & 7)) << 4);

    auto loadreg = [&](float4v (&d)[8], int tt) {
        int p = tt * 32 + srow; if (p > KP - 1) p = KP - 1;
        int ar = p - PAD_; ar = ar < 0 ? 0 : (ar > SEQ - 1 ? SEQ - 1 : ar);
        const float* s = A + (size_t)ar * DM + sc * 8;
#pragma unroll
        for (int j = 0; j < 4; j++) {
            d[2 * j]     = *(const float4v*)(s + j * 128);
            d[2 * j + 1] = *(const float4v*)(s + j * 128 + 4);
        }
    };

    float4v a[8];
    loadreg(a, t0);

    for (int ti = 0; ti < tcnt; ti++) {
        int tt = t0 + ti;
#pragma unroll
        for (int j = 0; j < 4; j++) {
            float4v f0 = a[2 * j], f1 = a[2 * j + 1];
            short8 h0;
            h0[0] = (short)bfc(f0.x); h0[1] = (short)bfc(f0.y);
            h0[2] = (short)bfc(f0.z); h0[3] = (short)bfc(f0.w);
            h0[4] = (short)bfc(f1.x); h0[5] = (short)bfc(f1.y);
            h0[6] = (short)bfc(f1.z); h0[7] = (short)bfc(f1.w);
            *(short8*)(lds + woff + j * 256) = h0;
        }
        if (ti + 1 < tcnt) loadreg(a, tt + 1);
        __builtin_amdgcn_sched_barrier(0);
        asm volatile("s_waitcnt lgkmcnt(0)" ::: "memory");
        __builtin_amdgcn_s_barrier();
        __builtin_amdgcn_sched_barrier(0);

        float4v acc[2][2];
#pragma unroll
        for (int mf = 0; mf < 2; mf++)
#pragma unroll
            for (int nf = 0; nf < 2; nf++) {
                float4v zz = {0.f, 0.f, 0.f, 0.f}; acc[mf][nf] = zz;
            }
#pragma unroll
        for (int s5 = 0; s5 < 16; s5++) {
            short8 afr[2];
#pragma unroll
            for (int mf = 0; mf < 2; mf++) {
                int row = mf * 16 + l15, c = s5 * 4 + g;
                afr[mf] = *(const short8*)(lds + row * 1024 + ((c ^ (row & 7)) << 4));
            }
#pragma unroll
            for (int mf = 0; mf < 2; mf++)
#pragma unroll
                for (int nf = 0; nf < 2; nf++)
                    acc[mf][nf] = MFMA16(afr[mf], Breg[nf][s5], acc[mf][nf], 0, 0, 0);
        }
        __builtin_amdgcn_s_barrier();
        __builtin_amdgcn_sched_barrier(0);

        int p0 = tt * 32;
        if (ten <= 1) {
            unsigned short* O = ten == 0 ? Qb : Kb;
#pragma unroll
            for (int nf = 0; nf < 2; nf++) {
                float bval = nf ? bias1 : bias0;
                int d = ((n0w + nf * 16) & 63) + l15;
                unsigned short* op = O + (size_t)hb2 * KP * 64 + d;
#pragma unroll
                for (int mf = 0; mf < 2; mf++) {
                    float4v vv = acc[mf][nf];
#pragma unroll
                    for (int r = 0; r < 4; r++) {
                        int p = p0 + mf * 16 + g * 4 + r;
                        if (p < KP)
                            op[(size_t)p * 64] = f2bf((vv[r] + bval) * scale);
                    }
                }
            }
        } else {
#pragma unroll
            for (int nf = 0; nf < 2; nf++) {
                float bval = nf ? bias1 : bias0;
                int d = ((n0w + nf * 16) & 63) + l15;
                unsigned short* base = VT + ((size_t)hb2 * 64 + d) * KP;
#pragma unroll
                for (int mf = 0; mf < 2; mf++) {
                    int p = p0 + mf * 16 + g * 4;
                    if (p <= KP - 4) {
                        float4v vv = acc[mf][nf];
                        ushort4v wv;
                        wv[0] = f2bf(vv.x + bval); wv[1] = f2bf(vv.y + bval);
                        wv[2] = f2bf(vv.z + bval); wv[3] = f2bf(vv.w + bval);
                        *(ushort4v*)(base + p) = wv;
                    }
                }
            }
        }
    }
}

// ============ kernel 2: windowed causal attention ============================
__global__ __launch_bounds__(384) void kattn(const unsigned short* __restrict__ Qb,
                                             const unsigned short* __restrict__ Kb,
                                             const unsigned short* __restrict__ VT,
                                             unsigned short* __restrict__ attn) {
    int win = blockIdx.x, hb = blockIdx.y;
    int h = hb >> 2, b = hb & 3;
    const unsigned short* Qg = Qb + (size_t)hb * KP * 64;
    const unsigned short* Kg = Kb + (size_t)hb * KP * 64;
    const unsigned short* Vt = VT + (size_t)hb * 64 * KP;
    int p0 = win * STEP_;

    // Ql [0,12288) 96x64; Kl [12288,28672) 128x64; Vl [28672,45056) 64x128;
    // Pl [45056,69632) 96x128. Ol reuses Ql.
    __shared__ __align__(16) char lds[69632];

    int tid = threadIdx.x, lane = tid & 63, f = tid >> 6;
    int l15 = lane & 15, g = lane >> 4;

#pragma unroll
    for (int it = 0; it < 5; it++) {
        int base = it * 384 + f * 64;
        if (base < 768) {                       // Q chunks
            int c = base + lane;
            int qi = c >> 3, kg = (c & 7) ^ (qi & 7);
            gload16(Qg + (size_t)(p0 + PAD_ + qi) * 64 + kg * 8, lds + base * 16);
        } else if (base < 1792) {               // K chunks
            int c = base + lane - 768;
            int x = c >> 3, kg = (c & 7) ^ (x & 7);
            gload16(Kg + (size_t)(p0 + x) * 64 + kg * 8, lds + base * 16);
        }
    }
    for (int c = tid; c < 2048; c += 384) {
        int d = c >> 5, c2 = c & 31;
        ushort4v wv = *(const ushort4v*)(Vt + (size_t)d * KP + p0 + c2 * 4);
        int cx = c2 >> 1;
        *(ushort4v*)(lds + 28672 + d * 256 + (((cx ^ (d & 7)) << 4) | ((c2 & 1) * 8))) = wv;
    }
    __syncthreads();

    short8 bq2[2];
    {
        int r = f * 16 + l15;
#pragma unroll
        for (int ks = 0; ks < 2; ks++) {
            int kg = ks * 4 + g;
            bq2[ks] = *(const short8*)(lds + r * 128 + ((kg ^ (r & 7)) << 4));
        }
    }
    float4v st[8];
#pragma unroll
    for (int xf = 0; xf < 8; xf++) {
        float4v zz = {0.f,0.f,0.f,0.f}; st[xf] = zz;
#pragma unroll
        for (int ks = 0; ks < 2; ks++) {
            int r = xf * 16 + l15;
            int kg = ks * 4 + g;
            short8 a = *(const short8*)(lds + 12288 + r * 128 + ((kg ^ (r & 7)) << 4));
            st[xf] = MFMA16(a, bq2[ks], st[xf], 0, 0, 0);
        }
    }

    int w_abs = PAD_ + f * 16 + l15;
    int w_eff = w_abs > 125 ? 125 : w_abs;
    float mx = -1e30f;
#pragma unroll
    for (int xf = 0; xf < 8; xf++)
#pragma unroll
        for (int r = 0; r < 4; r++) {
            int x = xf * 16 + g * 4 + r;
            float vv = st[xf][r];
            if (x > w_eff) vv = -1e30f;
            st[xf][r] = vv;
            mx = fmaxf(mx, vv);
        }
    mx = fmaxf(mx, __shfl_xor(mx, 16));
    mx = fmaxf(mx, __shfl_xor(mx, 32));
    float s = 0.f;
#pragma unroll
    for (int xf = 0; xf < 8; xf++)
#pragma unroll
        for (int r = 0; r < 4; r++) {
            float e = __expf(st[xf][r] - mx);
            st[xf][r] = e;
            s += e;
        }
    s += __shfl_xor(s, 16);
    s += __shfl_xor(s, 32);
    float inv = 1.f / s;

    {
        int qi = f * 16 + l15;
#pragma unroll
        for (int xf = 0; xf < 8; xf++) {
            ushort4v pw;
#pragma unroll
            for (int r = 0; r < 4; r++) pw[r] = f2bf(st[xf][r] * inv);
            int xc = 2 * xf + (g >> 1);
            *(ushort4v*)(lds + 45056 + qi * 256 + ((xc ^ (qi & 7)) << 4) + (g & 1) * 8) = pw;
        }
    }
    __syncthreads();

    float4v pv[4];
#pragma unroll
    for (int j = 0; j < 4; j++) { float4v zz = {0.f,0.f,0.f,0.f}; pv[j] = zz; }
    int qi = f * 16 + l15;
#pragma unroll
    for (int g2 = 0; g2 < 4; g2++) {
        int xc = g2 * 4 + g;
        short8 a = *(const short8*)(lds + 45056 + qi * 256 + ((xc ^ (qi & 7)) << 4));
#pragma unroll
        for (int j = 0; j < 4; j++) {
            int d = j * 16 + l15;
            short8 bvv = *(const short8*)(lds + 28672 + d * 256 + ((xc ^ (d & 7)) << 4));
            pv[j] = MFMA16(a, bvv, pv[j], 0, 0, 0);
        }
    }

    unsigned short* Ol = (unsigned short*)lds;
#pragma unroll
    for (int j = 0; j < 4; j++) {
        int d = j * 16 + l15;
#pragma unroll
        for (int r = 0; r < 4; r++) {
            int qq = f * 16 + g * 4 + r;
            int byte = qq * 128 + ((((d >> 3) ^ (qq & 7))) << 4) + (d & 7) * 2;
            *(unsigned short*)((char*)Ol + byte) = f2bf(pv[j][r]);
        }
    }
    __syncthreads();
    for (int c = tid; c < 672; c += 384) {
        int qq = c >> 3, ch = c & 7;
        short8 hv = *(const short8*)((char*)Ol + qq * 128 + ((ch ^ (qq & 7)) << 4));
        size_t off = ((size_t)(b * SEQ + win * STEP_ + qq) * DM) + h * 64 + ch * 8;
        *(short8*)(attn + off) = hv;
    }
}

// ============ kernel 3: weight-stationary output projection ==================
// Same template as kproj: wave holds W_o[32 n][512 k] in regs; A bf16 tile
// [32 m][512 k] reg->LDS staged with next-tile prefetch; f32 epilogue.
__global__ __launch_bounds__(512, 2) void kout(const unsigned short* __restrict__ Ab,
                                               const unsigned short* __restrict__ W,
                                               const float* __restrict__ bias,
                                               float* __restrict__ Out) {
    int L = blockIdx.x;                          // 0..703
    int P = (L >> 4) * 8 + (L & 7);
    int nhalf = (L >> 3) & 1;
    if (P >= OT_NBI) return;
    int t0 = P * OT_TPB;

    __shared__ __align__(16) char lds[32768];

    int tid = threadIdx.x, lane = tid & 63, w = tid >> 6;
    int l15 = lane & 15, g = lane >> 4;
    int n0w = nhalf * 256 + w * 32;

    short8 Breg[2][16];
#pragma unroll
    for (int nf = 0; nf < 2; nf++)
#pragma unroll
        for (int s5 = 0; s5 < 16; s5++)
            Breg[nf][s5] = *(const short8*)(W +
                (size_t)(n0w + nf * 16 + l15) * DM + s5 * 32 + g * 8);

    float bias0 = bias[n0w + l15];
    float bias1 = bias[n0w + 16 + l15];

    int srow = tid >> 4, sc = tid & 15;

    auto loadreg = [&](short8 (&d)[4], int tt) {
        const unsigned short* s = Ab + (size_t)(tt * 32 + srow) * DM;
#pragma unroll
        for (int j = 0; j < 4; j++)
            d[j] = *(const short8*)(s + (sc + j * 16) * 8);
    };

    short8 a[4];
    loadreg(a, t0);

    for (int ti = 0; ti < OT_TPB; ti++) {
        int tt = t0 + ti;
#pragma unroll
        for (int j = 0; j < 4; j++)
            *(short8*)(lds + srow * 1024 +
                       (((sc + j * 16) ^ (srow & 7)) << 4)) = a[j];
        if (ti + 1 < OT_TPB) loadreg(a, tt + 1);
        __builtin_amdgcn_sched_barrier(0);
        asm volatile("s_waitcnt lgkmcnt(0)" ::: "memory");
        __builtin_amdgcn_s_barrier();
        __builtin_amdgcn_sched_barrier(0);

        float4v acc[2][2];
#pragma unroll
        for (int mf = 0; mf < 2; mf++)
#pragma unroll
            for (int nf = 0; nf < 2; nf++) {
                float4v zz = {0.f, 0.f, 0.f, 0.f}; acc[mf][nf] = zz;
            }
#pragma unroll
        for (int s5 = 0; s5 < 16; s5++) {
            short8 afr[2];
#pragma unroll
            for (int mf = 0; mf < 2; mf++) {
                int row = mf * 16 + l15, c = s5 * 4 + g;
                afr[mf] = *(const short8*)(lds + row * 1024 + ((c ^ (row & 7)) << 4));
            }
#pragma unroll
            for (int mf = 0; mf < 2; mf++)
#pragma unroll
                for (int nf = 0; nf < 2; nf++)
                    acc[mf][nf] = MFMA16(afr[mf], Breg[nf][s5], acc[mf][nf], 0, 0, 0);
        }
        __builtin_amdgcn_s_barrier();
        __builtin_amdgcn_sched_barrier(0);

        int p0 = tt * 32;
#pragma unroll
        for (int nf = 0; nf < 2; nf++) {
            float bval = nf ? bias1 : bias0;
            int n = n0w + nf * 16 + l15;
#pragma unroll
            for (int mf = 0; mf < 2; mf++) {
                float4v vv = acc[mf][nf];
#pragma unroll
                for (int r = 0; r < 4; r++) {
                    int m = p0 + mf * 16 + g * 4 + r;
                    Out[(size_t)m * DM + n] = vv[r] + bval;
                }
            }
        }
    }
}

// ============ launch =========================================================
extern "C" void kernel_launch(void* const* d_in, const int* in_sizes, int n_in,
                              void* d_out, int out_size, void* d_ws, size_t ws_size,
                              hipStream_t stream) {
    const float* q  = (const float*)d_in[0];
    const float* k  = (const float*)d_in[1];
    const float* v  = (const float*)d_in[2];
    const float* Wq = (const float*)d_in[3];
    const float* bq = (const float*)d_in[4];
    const float* Wk = (const float*)d_in[5];
    const float* bk = (const float*)d_in[6];
    const float* Wv = (const float*)d_in[7];
    const float* bv = (const float*)d_in[8];
    const float* Wo = (const float*)d_in[9];
    const float* bo = (const float*)d_in[10];

    const size_t WT_ELEMS  = (size_t)4 * DM * DM;
    const size_t QKV_ELEMS = (size_t)32 * KP * 64;
    const size_t ATT_ELEMS = (size_t)MROWS * DM;
    size_t need = (WT_ELEMS + 3 * QKV_ELEMS + ATT_ELEMS) * 2;
    if (ws_size < need) return;

    unsigned short* Wt = (unsigned short*)d_ws;
    unsigned short* Qb = Wt + WT_ELEMS;
    unsigned short* Kb = Qb + QKV_ELEMS;
    unsigned short* VT = Kb + QKV_ELEMS;
    unsigned short* Ab = VT + QKV_ELEMS;

    kprep<<<dim3(8, 8, 4), dim3(256), 0, stream>>>(Wq, Wk, Wv, Wo, Wt);
    kproj<<<dim3(1008), dim3(512), 0, stream>>>(q, k, v, Wt, bq, bk, bv,
                                                Qb, Kb, VT);
    kattn<<<dim3(NWIN, 32), dim3(384), 0, stream>>>(Qb, Kb, VT, Ab);
    kout<<<dim3(704), dim3(512), 0, stream>>>(Ab, Wt + 3 * DM * DM, bo,
                                              (float*)d_out);
}

// Round 11
// 187.129 us; speedup vs baseline: 1.3518x; 1.2252x over previous
//
#include <hip/hip_runtime.h>
#include <hip/hip_bf16.h>
#include <stdint.h>

// ---- problem constants ----
#define BATCH 4
#define SEQ   8400
#define DM    512
#define KP    8484      // SEQ + 2*42 (edge pad)
#define NWIN  100
#define STEP_ 84
#define PAD_  42
#define NKEY  126
#define MROWS 33600     // BATCH*SEQ
#define NTILES 266      // ceil(KP/32)
#define TPB   13        // tiles per work unit (21*13 >= 266)  [R9 config]
#define NBI   21
#define OT_TPB 3        // kout tiles per work unit (350*3 = 1050 exact)
#define OT_NBI 350

typedef __attribute__((ext_vector_type(8))) short short8;
typedef __attribute__((ext_vector_type(4))) float float4v;
typedef __attribute__((ext_vector_type(4))) unsigned short ushort4v;

#define MFMA16 __builtin_amdgcn_mfma_f32_16x16x32_bf16

__device__ __forceinline__ unsigned short f2bf(float f) {
    union { float f; unsigned u; } v; v.f = f;
    return (unsigned short)((v.u + 0x7FFFu + ((v.u >> 16) & 1u)) >> 16);  // RNE
}
__device__ __forceinline__ unsigned short bfc(float f) {
    __hip_bfloat16 h = __float2bfloat16(f);
    union { __hip_bfloat16 h; unsigned short u; } v; v.h = h;
    return v.u;
}

typedef __attribute__((address_space(1))) const unsigned int as1_cu32;
typedef __attribute__((address_space(3))) unsigned int as3_u32;
__device__ __forceinline__ void gload16(const void* g, void* l) {
    __builtin_amdgcn_global_load_lds((as1_cu32*)g, (as3_u32*)l, 16, 0, 0);
}

// ============ prepass: W (f32 [k][n] 512x512) -> Wt (bf16 [n][k]) ============
__global__ __launch_bounds__(256) void kprep(const float* __restrict__ Wq,
                                             const float* __restrict__ Wk,
                                             const float* __restrict__ Wv,
                                             const float* __restrict__ Wo,
                                             unsigned short* __restrict__ Wt) {
    const float* src = blockIdx.z == 0 ? Wq : blockIdx.z == 1 ? Wk
                     : blockIdx.z == 2 ? Wv : Wo;
    unsigned short* dst = Wt + (size_t)blockIdx.z * DM * DM;
    __shared__ float t[64][65];
    int c = threadIdx.x & 63, r4 = threadIdx.x >> 6;
    int kb = blockIdx.x * 64, nb = blockIdx.y * 64;
    for (int i = 0; i < 16; i++) {
        int r = r4 * 16 + i;
        t[r][c] = src[(size_t)(kb + r) * DM + nb + c];
    }
    __syncthreads();
    for (int i = 0; i < 16; i++) {
        int r = r4 * 16 + i;
        dst[(size_t)(nb + r) * DM + kb + c] = f2bf(t[c][r]);
    }
}

// ============ kernel 1: weight-stationary fused pad+cvt+QKV projection =======
// R9 config: 512 blocks, TPB=13. 8 waves; wave holds B[32 n][512 k] in VGPRs.
__global__ __launch_bounds__(512, 2) void kproj(const float* __restrict__ q,
                                                const float* __restrict__ k,
                                                const float* __restrict__ v,
                                                const unsigned short* __restrict__ Wt,
                                                const float* __restrict__ bq,
                                                const float* __restrict__ bk,
                                                const float* __restrict__ bv,
                                                unsigned short* __restrict__ Qb,
                                                unsigned short* __restrict__ Kb,
                                                unsigned short* __restrict__ VT) {
    int L = blockIdx.x;                          // 0..511
    int P = (L >> 4) * 8 + (L & 7);              // work unit
    int nhalf = (L >> 3) & 1;
    if (P >= 12 * NBI) return;
    int z = P / NBI, bi = P % NBI;
    int ten = z >> 2, b = z & 3;
    int t0 = bi * TPB;
    int tcnt = NTILES - t0; if (tcnt > TPB) tcnt = TPB;
    if (tcnt <= 0) return;

    const float* A = (ten == 0 ? q : ten == 1 ? k : v) + (size_t)b * SEQ * DM;
    const unsigned short* Wten = Wt + (size_t)ten * DM * DM;
    const float* bias = ten == 0 ? bq : ten == 1 ? bk : bv;
    float scale = ten == 0 ? 0.07715167498104595f : 1.f;   // 1/sqrt(168)

    __shared__ __align__(16) char lds[32768];    // [32 rows][1024 B] bf16 swz

    int tid = threadIdx.x, lane = tid & 63, w = tid >> 6;
    int l15 = lane & 15, g = lane >> 4;
    int n0w = nhalf * 256 + w * 32;              // wave's 32-col slice
    int h = n0w >> 6;
    int hb2 = h * BATCH + b;

    // ---- B slice into registers (once per block)
    short8 Breg[2][16];
#pragma unroll
    for (int nf = 0; nf < 2; nf++)
#pragma unroll
        for (int s5 = 0; s5 < 16; s5++)
            Breg[nf][s5] = *(const short8*)(Wten +
                (size_t)(n0w + nf * 16 + l15) * DM + s5 * 32 + g * 8);

    float bias0 = bias[n0w + l15];
    float bias1 = bias[n0w + 16 + l15];

    int srow = tid >> 4, sc = tid & 15;
    int woff = srow * 1024 + ((sc ^ (srow & 7)) << 4);

    auto loadreg = [&](float4v (&d)[8], int tt) {
        int p = tt * 32 + srow; if (p > KP - 1) p = KP - 1;
        int ar = p - PAD_; ar = ar < 0 ? 0 : (ar > SEQ - 1 ? SEQ - 1 : ar);
        const float* s = A + (size_t)ar * DM + sc * 8;
#pragma unroll
        for (int j = 0; j < 4; j++) {
            d[2 * j]     = *(const float4v*)(s + j * 128);
            d[2 * j + 1] = *(const float4v*)(s + j * 128 + 4);
        }
    };

    float4v a[8];
    loadreg(a, t0);

    for (int ti = 0; ti < tcnt; ti++) {
        int tt = t0 + ti;
#pragma unroll
        for (int j = 0; j < 4; j++) {
            float4v f0 = a[2 * j], f1 = a[2 * j + 1];
            short8 h0;
            h0[0] = (short)bfc(f0.x); h0[1] = (short)bfc(f0.y);
            h0[2] = (short)bfc(f0.z); h0[3] = (short)bfc(f0.w);
            h0[4] = (short)bfc(f1.x); h0[5] = (short)bfc(f1.y);
            h0[6] = (short)bfc(f1.z); h0[7] = (short)bfc(f1.w);
            *(short8*)(lds + woff + j * 256) = h0;
        }
        if (ti + 1 < tcnt) loadreg(a, tt + 1);
        __builtin_amdgcn_sched_barrier(0);
        asm volatile("s_waitcnt lgkmcnt(0)" ::: "memory");
        __builtin_amdgcn_s_barrier();
        __builtin_amdgcn_sched_barrier(0);

        float4v acc[2][2];
#pragma unroll
        for (int mf = 0; mf < 2; mf++)
#pragma unroll
            for (int nf = 0; nf < 2; nf++) {
                float4v zz = {0.f, 0.f, 0.f, 0.f}; acc[mf][nf] = zz;
            }
#pragma unroll
        for (int s5 = 0; s5 < 16; s5++) {
            short8 afr[2];
#pragma unroll
            for (int mf = 0; mf < 2; mf++) {
                int row = mf * 16 + l15, c = s5 * 4 + g;
                afr[mf] = *(const short8*)(lds + row * 1024 + ((c ^ (row & 7)) << 4));
            }
#pragma unroll
            for (int mf = 0; mf < 2; mf++)
#pragma unroll
                for (int nf = 0; nf < 2; nf++)
                    acc[mf][nf] = MFMA16(afr[mf], Breg[nf][s5], acc[mf][nf], 0, 0, 0);
        }
        __builtin_amdgcn_s_barrier();
        __builtin_amdgcn_sched_barrier(0);

        int p0 = tt * 32;
        if (ten <= 1) {
            unsigned short* O = ten == 0 ? Qb : Kb;
#pragma unroll
            for (int nf = 0; nf < 2; nf++) {
                float bval = nf ? bias1 : bias0;
                int d = ((n0w + nf * 16) & 63) + l15;
                unsigned short* op = O + (size_t)hb2 * KP * 64 + d;
#pragma unroll
                for (int mf = 0; mf < 2; mf++) {
                    float4v vv = acc[mf][nf];
#pragma unroll
                    for (int r = 0; r < 4; r++) {
                        int p = p0 + mf * 16 + g * 4 + r;
                        if (p < KP)
                            op[(size_t)p * 64] = f2bf((vv[r] + bval) * scale);
                    }
                }
            }
        } else {
#pragma unroll
            for (int nf = 0; nf < 2; nf++) {
                float bval = nf ? bias1 : bias0;
                int d = ((n0w + nf * 16) & 63) + l15;
                unsigned short* base = VT + ((size_t)hb2 * 64 + d) * KP;
#pragma unroll
                for (int mf = 0; mf < 2; mf++) {
                    int p = p0 + mf * 16 + g * 4;
                    if (p <= KP - 4) {
                        float4v vv = acc[mf][nf];
                        ushort4v wv;
                        wv[0] = f2bf(vv.x + bval); wv[1] = f2bf(vv.y + bval);
                        wv[2] = f2bf(vv.z + bval); wv[3] = f2bf(vv.w + bval);
                        *(ushort4v*)(base + p) = wv;
                    }
                }
            }
        }
    }
}

// ============ kernel 2: windowed causal attention (44 KB LDS, 3 blocks/CU) ===
// Ql [0,12288) 96x64; Kl [12288,28672) 128x64; Vl [28672,45056) 64x128 swz.
// Pl aliases [0,24576) (Ql+Kl dead after QK^T; barrier before P write).
// P is wave-private (wave f owns rows f*16..f*16+15) -> no barrier P->PV,
// only lgkmcnt(0)+sched_barrier. Ol aliases [0,12288); barrier after PV.
__global__ __launch_bounds__(384) void kattn(const unsigned short* __restrict__ Qb,
                                             const unsigned short* __restrict__ Kb,
                                             const unsigned short* __restrict__ VT,
                                             unsigned short* __restrict__ attn) {
    int win = blockIdx.x, hb = blockIdx.y;
    int h = hb >> 2, b = hb & 3;
    const unsigned short* Qg = Qb + (size_t)hb * KP * 64;
    const unsigned short* Kg = Kb + (size_t)hb * KP * 64;
    const unsigned short* Vt = VT + (size_t)hb * 64 * KP;
    int p0 = win * STEP_;

    __shared__ __align__(16) char lds[45056];

    int tid = threadIdx.x, lane = tid & 63, f = tid >> 6;
    int l15 = lane & 15, g = lane >> 4;

    // ---- stage Q [0,12288) and K [12288,28672) via gload16
#pragma unroll
    for (int it = 0; it < 5; it++) {
        int base = it * 384 + f * 64;
        if (base < 768) {                       // Q chunks
            int c = base + lane;
            int qi = c >> 3, kg = (c & 7) ^ (qi & 7);
            gload16(Qg + (size_t)(p0 + PAD_ + qi) * 64 + kg * 8, lds + base * 16);
        } else if (base < 1792) {               // K chunks
            int c = base + lane - 768;
            int x = c >> 3, kg = (c & 7) ^ (x & 7);
            gload16(Kg + (size_t)(p0 + x) * 64 + kg * 8, lds + base * 16);
        }
    }
    // ---- stage V^T [28672,45056)
    for (int c = tid; c < 2048; c += 384) {
        int d = c >> 5, c2 = c & 31;
        ushort4v wv = *(const ushort4v*)(Vt + (size_t)d * KP + p0 + c2 * 4);
        int cx = c2 >> 1;
        *(ushort4v*)(lds + 28672 + d * 256 + (((cx ^ (d & 7)) << 4) | ((c2 & 1) * 8))) = wv;
    }
    __syncthreads();

    // ---- S^T = K @ Q^T
    short8 bq2[2];
    {
        int r = f * 16 + l15;
#pragma unroll
        for (int ks = 0; ks < 2; ks++) {
            int kg = ks * 4 + g;
            bq2[ks] = *(const short8*)(lds + r * 128 + ((kg ^ (r & 7)) << 4));
        }
    }
    float4v st[8];
#pragma unroll
    for (int xf = 0; xf < 8; xf++) {
        float4v zz = {0.f,0.f,0.f,0.f}; st[xf] = zz;
#pragma unroll
        for (int ks = 0; ks < 2; ks++) {
            int r = xf * 16 + l15;
            int kg = ks * 4 + g;
            short8 a = *(const short8*)(lds + 12288 + r * 128 + ((kg ^ (r & 7)) << 4));
            st[xf] = MFMA16(a, bq2[ks], st[xf], 0, 0, 0);
        }
    }

    // ---- causal mask + wave-local softmax (registers only)
    int w_abs = PAD_ + f * 16 + l15;
    int w_eff = w_abs > 125 ? 125 : w_abs;
    float mx = -1e30f;
#pragma unroll
    for (int xf = 0; xf < 8; xf++)
#pragma unroll
        for (int r = 0; r < 4; r++) {
            int x = xf * 16 + g * 4 + r;
            float vv = st[xf][r];
            if (x > w_eff) vv = -1e30f;
            st[xf][r] = vv;
            mx = fmaxf(mx, vv);
        }
    mx = fmaxf(mx, __shfl_xor(mx, 16));
    mx = fmaxf(mx, __shfl_xor(mx, 32));
    float s = 0.f;
#pragma unroll
    for (int xf = 0; xf < 8; xf++)
#pragma unroll
        for (int r = 0; r < 4; r++) {
            float e = __expf(st[xf][r] - mx);
            st[xf][r] = e;
            s += e;
        }
    s += __shfl_xor(s, 16);
    s += __shfl_xor(s, 32);
    float inv = 1.f / s;

    __syncthreads();   // all Ql/Kl reads done -> Pl may clobber [0,24576)

    // ---- P -> Pl [0,24576) bf16 [96 q][128 x] swz (wave-private rows)
    {
        int qi = f * 16 + l15;
#pragma unroll
        for (int xf = 0; xf < 8; xf++) {
            ushort4v pw;
#pragma unroll
            for (int r = 0; r < 4; r++) pw[r] = f2bf(st[xf][r] * inv);
            int xc = 2 * xf + (g >> 1);
            *(ushort4v*)(lds + qi * 256 + ((xc ^ (qi & 7)) << 4) + (g & 1) * 8) = pw;
        }
    }
    asm volatile("s_waitcnt lgkmcnt(0)" ::: "memory");
    __builtin_amdgcn_sched_barrier(0);

    // ---- PV (P rows are own-wave; V from [28672,...))
    float4v pv[4];
#pragma unroll
    for (int j = 0; j < 4; j++) { float4v zz = {0.f,0.f,0.f,0.f}; pv[j] = zz; }
    int qi = f * 16 + l15;
#pragma unroll
    for (int g2 = 0; g2 < 4; g2++) {
        int xc = g2 * 4 + g;
        short8 a = *(const short8*)(lds + qi * 256 + ((xc ^ (qi & 7)) << 4));
#pragma unroll
        for (int j = 0; j < 4; j++) {
            int d = j * 16 + l15;
            short8 bvv = *(const short8*)(lds + 28672 + d * 256 + ((xc ^ (d & 7)) << 4));
            pv[j] = MFMA16(a, bvv, pv[j], 0, 0, 0);
        }
    }

    __syncthreads();   // all PV reads of P done -> Ol may clobber [0,12288)

    // ---- bounce to Ol [0,12288) then coalesced global write
    unsigned short* Ol = (unsigned short*)lds;
#pragma unroll
    for (int j = 0; j < 4; j++) {
        int d = j * 16 + l15;
#pragma unroll
        for (int r = 0; r < 4; r++) {
            int qq = f * 16 + g * 4 + r;
            int byte = qq * 128 + ((((d >> 3) ^ (qq & 7))) << 4) + (d & 7) * 2;
            *(unsigned short*)((char*)Ol + byte) = f2bf(pv[j][r]);
        }
    }
    __syncthreads();
    for (int c = tid; c < 672; c += 384) {
        int qq = c >> 3, ch = c & 7;
        short8 hv = *(const short8*)((char*)Ol + qq * 128 + ((ch ^ (qq & 7)) << 4));
        size_t off = ((size_t)(b * SEQ + win * STEP_ + qq) * DM) + h * 64 + ch * 8;
        *(short8*)(attn + off) = hv;
    }
}

// ============ kernel 3: weight-stationary output projection ==================
__global__ __launch_bounds__(512, 2) void kout(const unsigned short* __restrict__ Ab,
                                               const unsigned short* __restrict__ W,
                                               const float* __restrict__ bias,
                                               float* __restrict__ Out) {
    int L = blockIdx.x;                          // 0..703
    int P = (L >> 4) * 8 + (L & 7);
    int nhalf = (L >> 3) & 1;
    if (P >= OT_NBI) return;
    int t0 = P * OT_TPB;

    __shared__ __align__(16) char lds[32768];

    int tid = threadIdx.x, lane = tid & 63, w = tid >> 6;
    int l15 = lane & 15, g = lane >> 4;
    int n0w = nhalf * 256 + w * 32;

    short8 Breg[2][16];
#pragma unroll
    for (int nf = 0; nf < 2; nf++)
#pragma unroll
        for (int s5 = 0; s5 < 16; s5++)
            Breg[nf][s5] = *(const short8*)(W +
                (size_t)(n0w + nf * 16 + l15) * DM + s5 * 32 + g * 8);

    float bias0 = bias[n0w + l15];
    float bias1 = bias[n0w + 16 + l15];

    int srow = tid >> 4, sc = tid & 15;

    auto loadreg = [&](short8 (&d)[4], int tt) {
        const unsigned short* s = Ab + (size_t)(tt * 32 + srow) * DM;
#pragma unroll
        for (int j = 0; j < 4; j++)
            d[j] = *(const short8*)(s + (sc + j * 16) * 8);
    };

    short8 a[4];
    loadreg(a, t0);

    for (int ti = 0; ti < OT_TPB; ti++) {
        int tt = t0 + ti;
#pragma unroll
        for (int j = 0; j < 4; j++)
            *(short8*)(lds + srow * 1024 +
                       (((sc + j * 16) ^ (srow & 7)) << 4)) = a[j];
        if (ti + 1 < OT_TPB) loadreg(a, tt + 1);
        __builtin_amdgcn_sched_barrier(0);
        asm volatile("s_waitcnt lgkmcnt(0)" ::: "memory");
        __builtin_amdgcn_s_barrier();
        __builtin_amdgcn_sched_barrier(0);

        float4v acc[2][2];
#pragma unroll
        for (int mf = 0; mf < 2; mf++)
#pragma unroll
            for (int nf = 0; nf < 2; nf++) {
                float4v zz = {0.f, 0.f, 0.f, 0.f}; acc[mf][nf] = zz;
            }
#pragma unroll
        for (int s5 = 0; s5 < 16; s5++) {
            short8 afr[2];
#pragma unroll
            for (int mf = 0; mf < 2; mf++) {
                int row = mf * 16 + l15, c = s5 * 4 + g;
                afr[mf] = *(const short8*)(lds + row * 1024 + ((c ^ (row & 7)) << 4));
            }
#pragma unroll
            for (int mf = 0; mf < 2; mf++)
#pragma unroll
                for (int nf = 0; nf < 2; nf++)
                    acc[mf][nf] = MFMA16(afr[mf], Breg[nf][s5], acc[mf][nf], 0, 0, 0);
        }
        __builtin_amdgcn_s_barrier();
        __builtin_amdgcn_sched_barrier(0);

        int p0 = tt * 32;
#pragma unroll
        for (int nf = 0; nf < 2; nf++) {
            float bval = nf ? bias1 : bias0;
            int n = n0w + nf * 16 + l15;
#pragma unroll
            for (int mf = 0; mf < 2; mf++) {
                float4v vv = acc[mf][nf];
#pragma unroll
                for (int r = 0; r < 4; r++) {
                    int m = p0 + mf * 16 + g * 4 + r;
                    Out[(size_t)m * DM + n] = vv[r] + bval;
                }
            }
        }
    }
}

// ============ launch =========================================================
extern "C" void kernel_launch(void* const* d_in, const int* in_sizes, int n_in,
                              void* d_out, int out_size, void* d_ws, size_t ws_size,
                              hipStream_t stream) {
    const float* q  = (const float*)d_in[0];
    const float* k  = (const float*)d_in[1];
    const float* v  = (const float*)d_in[2];
    const float* Wq = (const float*)d_in[3];
    const float* bq = (const float*)d_in[4];
    const float* Wk = (const float*)d_in[5];
    const float* bk = (const float*)d_in[6];
    const float* Wv = (const float*)d_in[7];
    const float* bv = (const float*)d_in[8];
    const float* Wo = (const float*)d_in[9];
    const float* bo = (const float*)d_in[10];

    const size_t WT_ELEMS  = (size_t)4 * DM * DM;
    const size_t QKV_ELEMS = (size_t)32 * KP * 64;
    const size_t ATT_ELEMS = (size_t)MROWS * DM;
    size_t need = (WT_ELEMS + 3 * QKV_ELEMS + ATT_ELEMS) * 2;
    if (ws_size < need) return;

    unsigned short* Wt = (unsigned short*)d_ws;
    unsigned short* Qb = Wt + WT_ELEMS;
    unsigned short* Kb = Qb + QKV_ELEMS;
    unsigned short* VT = Kb + QKV_ELEMS;
    unsigned short* Ab = VT + QKV_ELEMS;

    kprep<<<dim3(8, 8, 4), dim3(256), 0, stream>>>(Wq, Wk, Wv, Wo, Wt);
    kproj<<<dim3(512), dim3(512), 0, stream>>>(q, k, v, Wt, bq, bk, bv,
                                               Qb, Kb, VT);
    kattn<<<dim3(NWIN, 32), dim3(384), 0, stream>>>(Qb, Kb, VT, Ab);
    kout<<<dim3(704), dim3(512), 0, stream>>>(Ab, Wt + 3 * DM * DM, bo,
                                              (float*)d_out);
}